// Round 1
// baseline (3397.464 us; speedup 1.0000x reference)
//
#include <hip/hip_runtime.h>
#include <hip/hip_bf16.h>

#define HID 256
#define NCODES 18
#define SCAN_CHUNK 2048

// e-table: 18 distinct edge embeddings = ee1[a0] + ee2[a1]
__global__ void etab_kernel(const float* __restrict__ ee1, const float* __restrict__ ee2,
                            float* __restrict__ etab) {
    int t = blockIdx.x;
    int c = threadIdx.x;
    etab[t * HID + c] = ee1[(t / 3) * HID + c] + ee2[(t % 3) * HID + c];
}

// z[n] = xe1[x[n,0]] + xe2[x[n,1]]  (one wave per node, float4 per lane)
__global__ __launch_bounds__(256) void embed_kernel(const int* __restrict__ x,
                                                    const float* __restrict__ xe1,
                                                    const float* __restrict__ xe2,
                                                    float* __restrict__ z, int N) {
    int node = blockIdx.x * 4 + (threadIdx.x >> 6);
    int lane = threadIdx.x & 63;
    if (node >= N) return;
    int a0 = x[node * 2 + 0];
    int a1 = x[node * 2 + 1];
    const float4 u = *(const float4*)(xe1 + (size_t)a0 * HID + lane * 4);
    const float4 v = *(const float4*)(xe2 + (size_t)a1 * HID + lane * 4);
    float4 r;
    r.x = u.x + v.x; r.y = u.y + v.y; r.z = u.z + v.z; r.w = u.w + v.w;
    *(float4*)(z + (size_t)node * HID + lane * 4) = r;
}

__global__ void hist_kernel(const int* __restrict__ ei, int E, int* __restrict__ deg) {
    int i = blockIdx.x * 256 + threadIdx.x;
    if (i < E) atomicAdd(&deg[ei[E + i]], 1);
}

__global__ __launch_bounds__(256) void scan_partial(const int* __restrict__ deg, int n,
                                                    int* __restrict__ psum) {
    __shared__ int red[256];
    int base = blockIdx.x * SCAN_CHUNK;
    int s = 0;
    for (int i = threadIdx.x; i < SCAN_CHUNK; i += 256) {
        int idx = base + i;
        if (idx < n) s += deg[idx];
    }
    red[threadIdx.x] = s;
    __syncthreads();
    for (int off = 128; off > 0; off >>= 1) {
        if (threadIdx.x < off) red[threadIdx.x] += red[threadIdx.x + off];
        __syncthreads();
    }
    if (threadIdx.x == 0) psum[blockIdx.x] = red[0];
}

__global__ void scan_sums(int* psum, int nchunks) {
    if (blockIdx.x == 0 && threadIdx.x == 0) {
        int acc = 0;
        for (int i = 0; i < nchunks; i++) { int v = psum[i]; psum[i] = acc; acc += v; }
    }
}

__global__ __launch_bounds__(256) void scan_apply(const int* __restrict__ deg, int n,
                                                  const int* __restrict__ psum,
                                                  int* __restrict__ row_start,
                                                  int* __restrict__ cursor, int E) {
    __shared__ int tmp[256];
    int tid = threadIdx.x;
    int base = blockIdx.x * SCAN_CHUNK;
    int tb = base + tid * 8;
    int loc[8];
    int s = 0;
    for (int j = 0; j < 8; j++) {
        loc[j] = s;
        int idx = tb + j;
        if (idx < n) s += deg[idx];
    }
    tmp[tid] = s;
    __syncthreads();
    for (int off = 1; off < 256; off <<= 1) {
        int v = 0;
        if (tid >= off) v = tmp[tid - off];
        __syncthreads();
        if (tid >= off) tmp[tid] += v;
        __syncthreads();
    }
    int excl = tmp[tid] - s + psum[blockIdx.x];
    for (int j = 0; j < 8; j++) {
        int idx = tb + j;
        if (idx < n) {
            int v = excl + loc[j];
            row_start[idx] = v;
            cursor[idx] = v;
        }
    }
    if (blockIdx.x == 0 && tid == 0) row_start[n] = E;
}

// csr[p] = src | (code << 20), p slot-allocated per dst
__global__ void fill_kernel(const int* __restrict__ ei, const int* __restrict__ ea, int E,
                            int* __restrict__ cursor, unsigned* __restrict__ csr) {
    int i = blockIdx.x * 256 + threadIdx.x;
    if (i >= E) return;
    int dst = ei[E + i];
    int src = ei[i];
    int code = ea[i * 2] * 3 + ea[i * 2 + 1];
    int p = atomicAdd(&cursor[dst], 1);
    csr[p] = (unsigned)src | ((unsigned)code << 20);
}

// h0[n] = z[n] + sum_{in-edges} relu(z[src] + etab[code]); one wave per node
__global__ __launch_bounds__(256) void agg_kernel(const float* __restrict__ z,
                                                  const int* __restrict__ row_start,
                                                  const unsigned* __restrict__ csr,
                                                  const float* __restrict__ etab,
                                                  float* __restrict__ h0, int N) {
    int node = blockIdx.x * 4 + (threadIdx.x >> 6);
    int lane = threadIdx.x & 63;
    if (node >= N) return;
    float4 acc = *(const float4*)(z + (size_t)node * HID + lane * 4);
    int s = row_start[node];
    int e = row_start[node + 1];
    for (int i = s; i < e; i++) {
        unsigned p = csr[i];
        int src = p & 0xFFFFF;
        int code = p >> 20;
        float4 zv = *(const float4*)(z + (size_t)src * HID + lane * 4);
        float4 ev = *(const float4*)(etab + (size_t)code * HID + lane * 4);
        acc.x += fmaxf(zv.x + ev.x, 0.f);
        acc.y += fmaxf(zv.y + ev.y, 0.f);
        acc.z += fmaxf(zv.z + ev.z, 0.f);
        acc.w += fmaxf(zv.w + ev.w, 0.f);
    }
    *(float4*)(h0 + (size_t)node * HID + lane * 4) = acc;
}

// out = relu(A @ W + bias), A:[M,256] W:[256,256] row-major. fp32 vector GEMM.
#define BM 64
#define BN 64
#define BK 16
__global__ __launch_bounds__(256) void gemm_bias_relu(const float* __restrict__ A,
                                                      const float* __restrict__ W,
                                                      const float* __restrict__ bias,
                                                      float* __restrict__ out, int M) {
    __shared__ float As[BK][BM + 4];
    __shared__ float Bs[BK][BN + 4];
    int tid = threadIdx.x;
    int tn = tid & 15, tm = tid >> 4;
    int row0 = blockIdx.x * BM;
    int col0 = blockIdx.y * BN;
    float acc[4][4] = {};
    int am = tid >> 2;        // 0..63
    int ak = (tid & 3) * 4;   // 0,4,8,12
    int bk = tid >> 4;        // 0..15
    int bn = (tid & 15) * 4;  // 0..60

    for (int k0 = 0; k0 < HID; k0 += BK) {
        float4 av;
        int arow = row0 + am;
        if (arow < M) av = *(const float4*)(A + (size_t)arow * HID + k0 + ak);
        else av = make_float4(0.f, 0.f, 0.f, 0.f);
        As[ak + 0][am] = av.x;
        As[ak + 1][am] = av.y;
        As[ak + 2][am] = av.z;
        As[ak + 3][am] = av.w;
        float4 wv = *(const float4*)(W + (size_t)(k0 + bk) * HID + col0 + bn);
        *(float4*)&Bs[bk][bn] = wv;
        __syncthreads();
#pragma unroll
        for (int k = 0; k < BK; k++) {
            float4 a = *(const float4*)&As[k][tm * 4];
            float4 b = *(const float4*)&Bs[k][tn * 4];
            acc[0][0] += a.x * b.x; acc[0][1] += a.x * b.y; acc[0][2] += a.x * b.z; acc[0][3] += a.x * b.w;
            acc[1][0] += a.y * b.x; acc[1][1] += a.y * b.y; acc[1][2] += a.y * b.z; acc[1][3] += a.y * b.w;
            acc[2][0] += a.z * b.x; acc[2][1] += a.z * b.y; acc[2][2] += a.z * b.z; acc[2][3] += a.z * b.w;
            acc[3][0] += a.w * b.x; acc[3][1] += a.w * b.y; acc[3][2] += a.w * b.z; acc[3][3] += a.w * b.w;
        }
        __syncthreads();
    }
    float4 bb = *(const float4*)(bias + col0 + tn * 4);
#pragma unroll
    for (int i = 0; i < 4; i++) {
        int row = row0 + tm * 4 + i;
        if (row < M) {
            float4 r;
            r.x = fmaxf(acc[i][0] + bb.x, 0.f);
            r.y = fmaxf(acc[i][1] + bb.y, 0.f);
            r.z = fmaxf(acc[i][2] + bb.z, 0.f);
            r.w = fmaxf(acc[i][3] + bb.w, 0.f);
            *(float4*)(out + (size_t)row * HID + col0 + tn * 4) = r;
        }
    }
}

// per-graph mean pool; batch sorted -> binary search boundaries
__global__ __launch_bounds__(256) void pool_kernel(const float* __restrict__ z,
                                                   const int* __restrict__ batch, int N,
                                                   float* __restrict__ g) {
    int gid = blockIdx.x;
    int lo = 0, hi = N;
    while (lo < hi) { int mid = (lo + hi) >> 1; if (batch[mid] < gid) lo = mid + 1; else hi = mid; }
    int start = lo;
    int lo2 = start, hi2 = N;
    while (lo2 < hi2) { int mid = (lo2 + hi2) >> 1; if (batch[mid] < gid + 1) lo2 = mid + 1; else hi2 = mid; }
    int end = lo2;
    int cnt = end - start;
    int c = threadIdx.x;
    float acc = 0.f;
    for (int r = start; r < end; r++) acc += z[(size_t)r * HID + c];
    g[(size_t)gid * HID + c] = acc / fmaxf((float)cnt, 1.0f);
}

extern "C" void kernel_launch(void* const* d_in, const int* in_sizes, int n_in,
                              void* d_out, int out_size, void* d_ws, size_t ws_size,
                              hipStream_t stream) {
    const int* x = (const int*)d_in[0];
    const int* ei = (const int*)d_in[1];
    const int* ea = (const int*)d_in[2];
    const int* batch = (const int*)d_in[3];
    const float* xe1 = (const float*)d_in[4];
    const float* xe2 = (const float*)d_in[5];
    const float* ee1 = (const float*)d_in[6];
    const float* ee2 = (const float*)d_in[7];
    const float* W1 = (const float*)d_in[8];
    const float* b1 = (const float*)d_in[9];
    const float* W2 = (const float*)d_in[10];
    const float* b2 = (const float*)d_in[11];

    int N = in_sizes[0] / 2;
    int E = in_sizes[1] / 2;
    int G = out_size / HID - N;

    float* z = (float*)d_out;                          // [N,256]
    float* gout = (float*)d_out + (size_t)N * HID;     // [G,256]

    char* w = (char*)d_ws;
    float* h0 = (float*)w;   w += (size_t)N * HID * 4;
    float* y = (float*)w;    w += (size_t)N * HID * 4;
    float* etab = (float*)w; w += (size_t)NCODES * HID * 4;
    int* deg = (int*)w;      w += (size_t)N * 4;
    int* row_start = (int*)w; w += (size_t)(N + 1) * 4;
    int* cursor = (int*)w;   w += (size_t)N * 4;
    int* psum = (int*)w;     w += 64 * 4;
    unsigned* csr = (unsigned*)w;

    hipMemsetAsync(deg, 0, (size_t)N * 4, stream);
    etab_kernel<<<NCODES, HID, 0, stream>>>(ee1, ee2, etab);
    embed_kernel<<<(N + 3) / 4, 256, 0, stream>>>(x, xe1, xe2, z, N);
    hist_kernel<<<(E + 255) / 256, 256, 0, stream>>>(ei, E, deg);
    int nchunks = (N + SCAN_CHUNK - 1) / SCAN_CHUNK;
    scan_partial<<<nchunks, 256, 0, stream>>>(deg, N, psum);
    scan_sums<<<1, 1, 0, stream>>>(psum, nchunks);
    scan_apply<<<nchunks, 256, 0, stream>>>(deg, N, psum, row_start, cursor, E);
    fill_kernel<<<(E + 255) / 256, 256, 0, stream>>>(ei, ea, E, cursor, csr);

    int gm = (N + BM - 1) / BM;
    for (int l = 0; l < 5; l++) {
        agg_kernel<<<(N + 3) / 4, 256, 0, stream>>>(z, row_start, csr, etab, h0, N);
        gemm_bias_relu<<<dim3(gm, HID / BN), 256, 0, stream>>>(
            h0, W1 + (size_t)l * HID * HID, b1 + (size_t)l * HID, y, N);
        gemm_bias_relu<<<dim3(gm, HID / BN), 256, 0, stream>>>(
            y, W2 + (size_t)l * HID * HID, b2 + (size_t)l * HID, z, N);
    }
    pool_kernel<<<G, HID, 0, stream>>>(z, batch, N, gout);
}

// Round 2
// 1855.623 us; speedup vs baseline: 1.8309x; 1.8309x over previous
//
#include <hip/hip_runtime.h>
#include <hip/hip_bf16.h>

#define HID 256
#define NCODES 18
#define SCAN_CHUNK 2048

typedef _Float16 h8_t __attribute__((ext_vector_type(8)));
typedef _Float16 h4_t __attribute__((ext_vector_type(4)));
typedef float f4_t __attribute__((ext_vector_type(4)));

// e-table: 18 distinct edge embeddings = ee1[a0] + ee2[a1], fp16
__global__ void etab_kernel(const float* __restrict__ ee1, const float* __restrict__ ee2,
                            _Float16* __restrict__ etab) {
    int t = blockIdx.x;
    int c = threadIdx.x;
    etab[t * HID + c] = (_Float16)(ee1[(t / 3) * HID + c] + ee2[(t % 3) * HID + c]);
}

// zh[n] = fp16(xe1[x[n,0]] + xe2[x[n,1]])  (one wave per node)
__global__ __launch_bounds__(256) void embed_kernel(const int* __restrict__ x,
                                                    const float* __restrict__ xe1,
                                                    const float* __restrict__ xe2,
                                                    _Float16* __restrict__ zh, int N) {
    int node = blockIdx.x * 4 + (threadIdx.x >> 6);
    int lane = threadIdx.x & 63;
    if (node >= N) return;
    int a0 = x[node * 2 + 0];
    int a1 = x[node * 2 + 1];
    const float4 u = *(const float4*)(xe1 + (size_t)a0 * HID + lane * 4);
    const float4 v = *(const float4*)(xe2 + (size_t)a1 * HID + lane * 4);
    h4_t r;
    r.x = (_Float16)(u.x + v.x); r.y = (_Float16)(u.y + v.y);
    r.z = (_Float16)(u.z + v.z); r.w = (_Float16)(u.w + v.w);
    *(h4_t*)(zh + (size_t)node * HID + lane * 4) = r;
}

// W [5][256][256] fp32 row-major -> Wt [5][256][256] fp16 TRANSPOSED (Wt[n][k]=W[k][n])
__global__ __launch_bounds__(256) void prep_w(const float* __restrict__ W,
                                              _Float16* __restrict__ Wt) {
    __shared__ float t[32][33];
    int m = blockIdx.z;
    int tx = threadIdx.x & 31, ty = threadIdx.x >> 5;   // 32 x 8
    const float* Wm = W + (size_t)m * HID * HID;
    _Float16* Wtm = Wt + (size_t)m * HID * HID;
    int k0 = blockIdx.x * 32, n0 = blockIdx.y * 32;
#pragma unroll
    for (int j = 0; j < 4; ++j) { int r = ty + j * 8; t[r][tx] = Wm[(k0 + r) * HID + n0 + tx]; }
    __syncthreads();
#pragma unroll
    for (int j = 0; j < 4; ++j) { int r = ty + j * 8; Wtm[(size_t)(n0 + r) * HID + k0 + tx] = (_Float16)t[tx][r]; }
}

__global__ void hist_kernel(const int* __restrict__ ei, int E, int* __restrict__ deg) {
    int i = blockIdx.x * 256 + threadIdx.x;
    if (i < E) atomicAdd(&deg[ei[E + i]], 1);
}

__global__ __launch_bounds__(256) void scan_partial(const int* __restrict__ deg, int n,
                                                    int* __restrict__ psum) {
    __shared__ int red[256];
    int base = blockIdx.x * SCAN_CHUNK;
    int s = 0;
    for (int i = threadIdx.x; i < SCAN_CHUNK; i += 256) {
        int idx = base + i;
        if (idx < n) s += deg[idx];
    }
    red[threadIdx.x] = s;
    __syncthreads();
    for (int off = 128; off > 0; off >>= 1) {
        if (threadIdx.x < off) red[threadIdx.x] += red[threadIdx.x + off];
        __syncthreads();
    }
    if (threadIdx.x == 0) psum[blockIdx.x] = red[0];
}

__global__ void scan_sums(int* psum, int nchunks) {
    if (blockIdx.x == 0 && threadIdx.x == 0) {
        int acc = 0;
        for (int i = 0; i < nchunks; i++) { int v = psum[i]; psum[i] = acc; acc += v; }
    }
}

__global__ __launch_bounds__(256) void scan_apply(const int* __restrict__ deg, int n,
                                                  const int* __restrict__ psum,
                                                  int* __restrict__ row_start,
                                                  int* __restrict__ cursor, int E) {
    __shared__ int tmp[256];
    int tid = threadIdx.x;
    int base = blockIdx.x * SCAN_CHUNK;
    int tb = base + tid * 8;
    int loc[8];
    int s = 0;
    for (int j = 0; j < 8; j++) {
        loc[j] = s;
        int idx = tb + j;
        if (idx < n) s += deg[idx];
    }
    tmp[tid] = s;
    __syncthreads();
    for (int off = 1; off < 256; off <<= 1) {
        int v = 0;
        if (tid >= off) v = tmp[tid - off];
        __syncthreads();
        if (tid >= off) tmp[tid] += v;
        __syncthreads();
    }
    int excl = tmp[tid] - s + psum[blockIdx.x];
    for (int j = 0; j < 8; j++) {
        int idx = tb + j;
        if (idx < n) {
            int v = excl + loc[j];
            row_start[idx] = v;
            cursor[idx] = v;
        }
    }
    if (blockIdx.x == 0 && tid == 0) row_start[n] = E;
}

// csr[p] = src | (code << 20)
__global__ void fill_kernel(const int* __restrict__ ei, const int* __restrict__ ea, int E,
                            int* __restrict__ cursor, unsigned* __restrict__ csr) {
    int i = blockIdx.x * 256 + threadIdx.x;
    if (i >= E) return;
    int dst = ei[E + i];
    int src = ei[i];
    int code = ea[i * 2] * 3 + ea[i * 2 + 1];
    int p = atomicAdd(&cursor[dst], 1);
    csr[p] = (unsigned)src | ((unsigned)code << 20);
}

// h0h[n] = fp16( zh[n] + sum_in relu(zh[src] + etab[code]) ); one wave per node, fp32 accum
__global__ __launch_bounds__(256) void agg_kernel(const _Float16* __restrict__ zh,
                                                  const int* __restrict__ row_start,
                                                  const unsigned* __restrict__ csr,
                                                  const _Float16* __restrict__ etab,
                                                  _Float16* __restrict__ h0h, int N) {
    int node = blockIdx.x * 4 + (threadIdx.x >> 6);
    int lane = threadIdx.x & 63;
    if (node >= N) return;
    h4_t self = *(const h4_t*)(zh + (size_t)node * HID + lane * 4);
    float ax = (float)self.x, ay = (float)self.y, az = (float)self.z, aw = (float)self.w;
    int s = __builtin_amdgcn_readfirstlane(row_start[node]);
    int e = __builtin_amdgcn_readfirstlane(row_start[node + 1]);
    for (int i = s; i < e; ++i) {
        unsigned p = csr[i];
        int src = p & 0xFFFFF;
        int code = p >> 20;
        h4_t zv = *(const h4_t*)(zh + (size_t)src * HID + lane * 4);
        h4_t ev = *(const h4_t*)(etab + (size_t)code * HID + lane * 4);
        ax += fmaxf((float)zv.x + (float)ev.x, 0.f);
        ay += fmaxf((float)zv.y + (float)ev.y, 0.f);
        az += fmaxf((float)zv.z + (float)ev.z, 0.f);
        aw += fmaxf((float)zv.w + (float)ev.w, 0.f);
    }
    h4_t o;
    o.x = (_Float16)ax; o.y = (_Float16)ay; o.z = (_Float16)az; o.w = (_Float16)aw;
    *(h4_t*)(h0h + (size_t)node * HID + lane * 4) = o;
}

// out = relu(A @ W + b).  A:[M,256] fp16 row-major, Wt:[256,256] fp16 = W^T.
// Block: 256 thr / 4 waves, 128-row A tile in LDS (XOR-swizzled 16B chunks),
// wave tile 64x64, mfma_f32_16x16x32_f16, fp32 accum. Writes fp16 (+optional fp32).
__global__ __launch_bounds__(256) void gemm_mfma(const _Float16* __restrict__ A,
                                                 const _Float16* __restrict__ Wt,
                                                 const float* __restrict__ bias,
                                                 _Float16* __restrict__ outh,
                                                 float* __restrict__ outf,
                                                 int M, int writef) {
    __shared__ _Float16 As[128 * HID];   // 64 KB, chunk-swizzled
    int tid = threadIdx.x;
    int lane = tid & 63;
    int w = tid >> 6;
    int row0 = blockIdx.x * 128;
    const _Float16* Ab = A + (size_t)row0 * HID;

    // stage: chunk c (16B) holds global chunk (row, cir) at LDS slot (row, cir^(row&7))
#pragma unroll
    for (int it = 0; it < 16; ++it) {
        int c = it * 256 + tid;
        int row = c >> 5, cir = c & 31;
        h8_t v = *(const h8_t*)(Ab + row * HID + cir * 8);
        int dst = row * 32 + (cir ^ (row & 7));
        *(h8_t*)(As + dst * 8) = v;
    }
    __syncthreads();

    int wr = (w >> 1) * 64;
    int wc = (w & 1) * 64;
    int l16 = lane & 15;
    int lq = lane >> 4;   // 0..3

    for (int cb = 0; cb < 2; ++cb) {
        f4_t acc[4][4] = {};
#pragma unroll
        for (int ks = 0; ks < 8; ++ks) {
            h8_t a[4], b[4];
#pragma unroll
            for (int mi = 0; mi < 4; ++mi) {
                int row = wr + mi * 16 + l16;
                int kc = ks * 4 + lq;
                int ch = row * 32 + (kc ^ (row & 7));
                a[mi] = *(const h8_t*)(As + ch * 8);
            }
#pragma unroll
            for (int ni = 0; ni < 4; ++ni) {
                int col = cb * 128 + wc + ni * 16 + l16;
                b[ni] = *(const h8_t*)(Wt + (size_t)col * HID + ks * 32 + lq * 8);
            }
#pragma unroll
            for (int mi = 0; mi < 4; ++mi)
#pragma unroll
                for (int ni = 0; ni < 4; ++ni)
                    acc[mi][ni] = __builtin_amdgcn_mfma_f32_16x16x32_f16(a[mi], b[ni], acc[mi][ni], 0, 0, 0);
        }
#pragma unroll
        for (int ni = 0; ni < 4; ++ni) {
            int col = cb * 128 + wc + ni * 16 + l16;
            float bv = bias[col];
#pragma unroll
            for (int mi = 0; mi < 4; ++mi) {
                int rb = row0 + wr + mi * 16 + lq * 4;
#pragma unroll
                for (int r = 0; r < 4; ++r) {
                    int row = rb + r;
                    if (row < M) {
                        float v = fmaxf(acc[mi][ni][r] + bv, 0.f);
                        outh[(size_t)row * HID + col] = (_Float16)v;
                        if (writef) outf[(size_t)row * HID + col] = v;
                    }
                }
            }
        }
    }
}

// per-graph mean pool from fp32 z (d_out)
__global__ __launch_bounds__(256) void pool_kernel(const float* __restrict__ z,
                                                   const int* __restrict__ batch, int N,
                                                   float* __restrict__ g) {
    int gid = blockIdx.x;
    int lo = 0, hi = N;
    while (lo < hi) { int mid = (lo + hi) >> 1; if (batch[mid] < gid) lo = mid + 1; else hi = mid; }
    int start = lo;
    int lo2 = start, hi2 = N;
    while (lo2 < hi2) { int mid = (lo2 + hi2) >> 1; if (batch[mid] < gid + 1) lo2 = mid + 1; else hi2 = mid; }
    int end = lo2;
    int cnt = end - start;
    int c = threadIdx.x;
    float acc = 0.f;
    for (int r = start; r < end; r++) acc += z[(size_t)r * HID + c];
    g[(size_t)gid * HID + c] = acc / fmaxf((float)cnt, 1.0f);
}

extern "C" void kernel_launch(void* const* d_in, const int* in_sizes, int n_in,
                              void* d_out, int out_size, void* d_ws, size_t ws_size,
                              hipStream_t stream) {
    const int* x = (const int*)d_in[0];
    const int* ei = (const int*)d_in[1];
    const int* ea = (const int*)d_in[2];
    const int* batch = (const int*)d_in[3];
    const float* xe1 = (const float*)d_in[4];
    const float* xe2 = (const float*)d_in[5];
    const float* ee1 = (const float*)d_in[6];
    const float* ee2 = (const float*)d_in[7];
    const float* W1 = (const float*)d_in[8];
    const float* b1 = (const float*)d_in[9];
    const float* W2 = (const float*)d_in[10];
    const float* b2 = (const float*)d_in[11];

    int N = in_sizes[0] / 2;
    int E = in_sizes[1] / 2;
    int G = out_size / HID - N;
    int nbm = (N + 127) / 128;
    int Np = nbm * 128;

    float* z = (float*)d_out;                       // [N,256] fp32 (final layer only)
    float* gout = z + (size_t)N * HID;              // [G,256]

    char* w = (char*)d_ws;
    _Float16* h0h = (_Float16*)w;  w += (size_t)Np * HID * 2;
    _Float16* yh  = (_Float16*)w;  w += (size_t)Np * HID * 2;
    _Float16* zh  = (_Float16*)w;  w += (size_t)Np * HID * 2;
    _Float16* Wt1 = (_Float16*)w;  w += (size_t)5 * HID * HID * 2;
    _Float16* Wt2 = (_Float16*)w;  w += (size_t)5 * HID * HID * 2;
    _Float16* etabh = (_Float16*)w; w += (size_t)NCODES * HID * 2;
    int* deg = (int*)w;       w += (size_t)N * 4;
    int* row_start = (int*)w; w += (size_t)(N + 1) * 4;
    int* cursor = (int*)w;    w += (size_t)N * 4;
    int* psum = (int*)w;      w += 64 * 4;
    unsigned* csr = (unsigned*)w;

    hipMemsetAsync(deg, 0, (size_t)N * 4, stream);
    etab_kernel<<<NCODES, HID, 0, stream>>>(ee1, ee2, etabh);
    embed_kernel<<<(N + 3) / 4, 256, 0, stream>>>(x, xe1, xe2, zh, N);
    prep_w<<<dim3(8, 8, 5), 256, 0, stream>>>(W1, Wt1);
    prep_w<<<dim3(8, 8, 5), 256, 0, stream>>>(W2, Wt2);
    hist_kernel<<<(E + 255) / 256, 256, 0, stream>>>(ei, E, deg);
    int nchunks = (N + SCAN_CHUNK - 1) / SCAN_CHUNK;
    scan_partial<<<nchunks, 256, 0, stream>>>(deg, N, psum);
    scan_sums<<<1, 1, 0, stream>>>(psum, nchunks);
    scan_apply<<<nchunks, 256, 0, stream>>>(deg, N, psum, row_start, cursor, E);
    fill_kernel<<<(E + 255) / 256, 256, 0, stream>>>(ei, ea, E, cursor, csr);

    for (int l = 0; l < 5; l++) {
        agg_kernel<<<(N + 3) / 4, 256, 0, stream>>>(zh, row_start, csr, etabh, h0h, N);
        gemm_mfma<<<nbm, 256, 0, stream>>>(h0h, Wt1 + (size_t)l * HID * HID,
                                           b1 + (size_t)l * HID, yh, (float*)0, N, 0);
        gemm_mfma<<<nbm, 256, 0, stream>>>(yh, Wt2 + (size_t)l * HID * HID,
                                           b2 + (size_t)l * HID, zh, z, N, (l == 4) ? 1 : 0);
    }
    pool_kernel<<<G, HID, 0, stream>>>(z, batch, N, gout);
}

// Round 3
// 1708.073 us; speedup vs baseline: 1.9891x; 1.0864x over previous
//
#include <hip/hip_runtime.h>
#include <hip/hip_bf16.h>

#define HID 256
#define NCODES 18
#define SCAN_CHUNK 2048

typedef _Float16 h8_t __attribute__((ext_vector_type(8)));
typedef _Float16 h4_t __attribute__((ext_vector_type(4)));
typedef float f4_t __attribute__((ext_vector_type(4)));

// e-table: 18 distinct edge embeddings = ee1[a0] + ee2[a1], fp16
__global__ void etab_kernel(const float* __restrict__ ee1, const float* __restrict__ ee2,
                            _Float16* __restrict__ etab) {
    int t = blockIdx.x;
    int c = threadIdx.x;
    etab[t * HID + c] = (_Float16)(ee1[(t / 3) * HID + c] + ee2[(t % 3) * HID + c]);
}

// zh[n] = fp16(xe1[x[n,0]] + xe2[x[n,1]])
__global__ __launch_bounds__(256) void embed_kernel(const int* __restrict__ x,
                                                    const float* __restrict__ xe1,
                                                    const float* __restrict__ xe2,
                                                    _Float16* __restrict__ zh, int N) {
    int node = blockIdx.x * 4 + (threadIdx.x >> 6);
    int lane = threadIdx.x & 63;
    if (node >= N) return;
    int a0 = x[node * 2 + 0];
    int a1 = x[node * 2 + 1];
    const float4 u = *(const float4*)(xe1 + (size_t)a0 * HID + lane * 4);
    const float4 v = *(const float4*)(xe2 + (size_t)a1 * HID + lane * 4);
    h4_t r;
    r.x = (_Float16)(u.x + v.x); r.y = (_Float16)(u.y + v.y);
    r.z = (_Float16)(u.z + v.z); r.w = (_Float16)(u.w + v.w);
    *(h4_t*)(zh + (size_t)node * HID + lane * 4) = r;
}

// W [5][256][256] fp32 row-major -> Wt fp16 transposed (Wt[n][k]=W[k][n])
__global__ __launch_bounds__(256) void prep_w(const float* __restrict__ W,
                                              _Float16* __restrict__ Wt) {
    __shared__ float t[32][33];
    int m = blockIdx.z;
    int tx = threadIdx.x & 31, ty = threadIdx.x >> 5;
    const float* Wm = W + (size_t)m * HID * HID;
    _Float16* Wtm = Wt + (size_t)m * HID * HID;
    int k0 = blockIdx.x * 32, n0 = blockIdx.y * 32;
#pragma unroll
    for (int j = 0; j < 4; ++j) { int r = ty + j * 8; t[r][tx] = Wm[(k0 + r) * HID + n0 + tx]; }
    __syncthreads();
#pragma unroll
    for (int j = 0; j < 4; ++j) { int r = ty + j * 8; Wtm[(size_t)(n0 + r) * HID + k0 + tx] = (_Float16)t[tx][r]; }
}

__global__ void hist_kernel(const int* __restrict__ ei, int E, int* __restrict__ deg) {
    int i = blockIdx.x * 256 + threadIdx.x;
    if (i < E) atomicAdd(&deg[ei[E + i]], 1);
}

__global__ __launch_bounds__(256) void scan_partial(const int* __restrict__ deg, int n,
                                                    int* __restrict__ psum) {
    __shared__ int red[256];
    int base = blockIdx.x * SCAN_CHUNK;
    int s = 0;
    for (int i = threadIdx.x; i < SCAN_CHUNK; i += 256) {
        int idx = base + i;
        if (idx < n) s += deg[idx];
    }
    red[threadIdx.x] = s;
    __syncthreads();
    for (int off = 128; off > 0; off >>= 1) {
        if (threadIdx.x < off) red[threadIdx.x] += red[threadIdx.x + off];
        __syncthreads();
    }
    if (threadIdx.x == 0) psum[blockIdx.x] = red[0];
}

__global__ void scan_sums(int* psum, int nchunks) {
    if (blockIdx.x == 0 && threadIdx.x == 0) {
        int acc = 0;
        for (int i = 0; i < nchunks; i++) { int v = psum[i]; psum[i] = acc; acc += v; }
    }
}

__global__ __launch_bounds__(256) void scan_apply(const int* __restrict__ deg, int n,
                                                  const int* __restrict__ psum,
                                                  int* __restrict__ row_start,
                                                  int* __restrict__ cursor, int E) {
    __shared__ int tmp[256];
    int tid = threadIdx.x;
    int base = blockIdx.x * SCAN_CHUNK;
    int tb = base + tid * 8;
    int loc[8];
    int s = 0;
    for (int j = 0; j < 8; j++) {
        loc[j] = s;
        int idx = tb + j;
        if (idx < n) s += deg[idx];
    }
    tmp[tid] = s;
    __syncthreads();
    for (int off = 1; off < 256; off <<= 1) {
        int v = 0;
        if (tid >= off) v = tmp[tid - off];
        __syncthreads();
        if (tid >= off) tmp[tid] += v;
        __syncthreads();
    }
    int excl = tmp[tid] - s + psum[blockIdx.x];
    for (int j = 0; j < 8; j++) {
        int idx = tb + j;
        if (idx < n) {
            int v = excl + loc[j];
            row_start[idx] = v;
            cursor[idx] = v;
        }
    }
    if (blockIdx.x == 0 && tid == 0) row_start[n] = E;
}

__global__ void fill_kernel(const int* __restrict__ ei, const int* __restrict__ ea, int E,
                            int* __restrict__ cursor, unsigned* __restrict__ csr) {
    int i = blockIdx.x * 256 + threadIdx.x;
    if (i >= E) return;
    int dst = ei[E + i];
    int src = ei[i];
    int code = ea[i * 2] * 3 + ea[i * 2 + 1];
    int p = atomicAdd(&cursor[dst], 1);
    csr[p] = (unsigned)src | ((unsigned)code << 20);
}

// h0h[n] = fp16( zh[n] + sum_in relu(zh[src]+etab[code]) )
// 2 nodes per wave (32 lanes each, h8 = 16B loads), edge loop unrolled x2.
__global__ __launch_bounds__(256) void agg_kernel(const _Float16* __restrict__ zh,
                                                  const int* __restrict__ row_start,
                                                  const unsigned* __restrict__ csr,
                                                  const _Float16* __restrict__ etab,
                                                  _Float16* __restrict__ h0h, int N) {
    int tid = threadIdx.x;
    int node = blockIdx.x * 8 + (tid >> 5);  // wave covers 2 nodes via halves
    int l32 = tid & 31;
    if (node >= N) return;
    h8_t self = *(const h8_t*)(zh + (size_t)node * HID + l32 * 8);
    float acc[8];
#pragma unroll
    for (int j = 0; j < 8; ++j) acc[j] = (float)self[j];
    int s = row_start[node];
    int e = row_start[node + 1];
    int i = s;
    for (; i + 2 <= e; i += 2) {
        unsigned p0 = csr[i], p1 = csr[i + 1];
        h8_t z0 = *(const h8_t*)(zh + (size_t)(p0 & 0xFFFFF) * HID + l32 * 8);
        h8_t e0 = *(const h8_t*)(etab + (size_t)(p0 >> 20) * HID + l32 * 8);
        h8_t z1 = *(const h8_t*)(zh + (size_t)(p1 & 0xFFFFF) * HID + l32 * 8);
        h8_t e1 = *(const h8_t*)(etab + (size_t)(p1 >> 20) * HID + l32 * 8);
#pragma unroll
        for (int j = 0; j < 8; ++j) {
            acc[j] += fmaxf((float)z0[j] + (float)e0[j], 0.f);
            acc[j] += fmaxf((float)z1[j] + (float)e1[j], 0.f);
        }
    }
    if (i < e) {
        unsigned p0 = csr[i];
        h8_t z0 = *(const h8_t*)(zh + (size_t)(p0 & 0xFFFFF) * HID + l32 * 8);
        h8_t e0 = *(const h8_t*)(etab + (size_t)(p0 >> 20) * HID + l32 * 8);
#pragma unroll
        for (int j = 0; j < 8; ++j) acc[j] += fmaxf((float)z0[j] + (float)e0[j], 0.f);
    }
    h8_t o;
#pragma unroll
    for (int j = 0; j < 8; ++j) o[j] = (_Float16)acc[j];
    *(h8_t*)(h0h + (size_t)node * HID + l32 * 8) = o;
}

// Fused MLP: z = relu( relu(A@W1+b1) @ W2 + b2 ).  A fp16 [M,256]; Wt* = W*^T fp16.
// 128-row tile in LDS (XOR-swizzled 16B chunks); y kept in a second LDS buffer.
__global__ __launch_bounds__(256) void mlp_fused(const _Float16* __restrict__ A,
                                                 const _Float16* __restrict__ Wt1,
                                                 const float* __restrict__ b1,
                                                 const _Float16* __restrict__ Wt2,
                                                 const float* __restrict__ b2,
                                                 _Float16* __restrict__ outh,
                                                 float* __restrict__ outf,
                                                 int M, int writef) {
    __shared__ _Float16 As[128 * HID];   // 64 KB
    __shared__ _Float16 Ys[128 * HID];   // 64 KB
    int tid = threadIdx.x;
    int lane = tid & 63;
    int w = tid >> 6;
    int row0 = blockIdx.x * 128;
    const _Float16* Ab = A + (size_t)row0 * HID;

#pragma unroll
    for (int it = 0; it < 16; ++it) {
        int c = it * 256 + tid;
        int row = c >> 5, cir = c & 31;
        h8_t v = *(const h8_t*)(Ab + row * HID + cir * 8);
        *(h8_t*)(As + (row * 32 + (cir ^ (row & 7))) * 8) = v;
    }
    __syncthreads();

    int wr = (w >> 1) * 64;
    int wc = (w & 1) * 64;
    int l16 = lane & 15;
    int lq = lane >> 4;

    // ---- GEMM1: y = relu(A@W1+b1) -> Ys (swizzled fp16) ----
    for (int cb = 0; cb < 2; ++cb) {
        f4_t acc[4][4] = {};
#pragma unroll
        for (int ks = 0; ks < 8; ++ks) {
            h8_t a[4], b[4];
#pragma unroll
            for (int mi = 0; mi < 4; ++mi) {
                int row = wr + mi * 16 + l16;
                int kc = ks * 4 + lq;
                a[mi] = *(const h8_t*)(As + (row * 32 + (kc ^ (row & 7))) * 8);
            }
#pragma unroll
            for (int ni = 0; ni < 4; ++ni) {
                int col = cb * 128 + wc + ni * 16 + l16;
                b[ni] = *(const h8_t*)(Wt1 + (size_t)col * HID + ks * 32 + lq * 8);
            }
#pragma unroll
            for (int mi = 0; mi < 4; ++mi)
#pragma unroll
                for (int ni = 0; ni < 4; ++ni)
                    acc[mi][ni] = __builtin_amdgcn_mfma_f32_16x16x32_f16(a[mi], b[ni], acc[mi][ni], 0, 0, 0);
        }
#pragma unroll
        for (int ni = 0; ni < 4; ++ni) {
            int col = cb * 128 + wc + ni * 16 + l16;
            float bv = b1[col];
            int cir = col >> 3, cil = col & 7;
#pragma unroll
            for (int mi = 0; mi < 4; ++mi) {
                int rb = wr + mi * 16 + lq * 4;
#pragma unroll
                for (int r = 0; r < 4; ++r) {
                    int rr = rb + r;
                    Ys[(rr * 32 + (cir ^ (rr & 7))) * 8 + cil] =
                        (_Float16)fmaxf(acc[mi][ni][r] + bv, 0.f);
                }
            }
        }
    }
    __syncthreads();

    // ---- GEMM2: z = relu(y@W2+b2) -> global ----
    for (int cb = 0; cb < 2; ++cb) {
        f4_t acc[4][4] = {};
#pragma unroll
        for (int ks = 0; ks < 8; ++ks) {
            h8_t a[4], b[4];
#pragma unroll
            for (int mi = 0; mi < 4; ++mi) {
                int row = wr + mi * 16 + l16;
                int kc = ks * 4 + lq;
                a[mi] = *(const h8_t*)(Ys + (row * 32 + (kc ^ (row & 7))) * 8);
            }
#pragma unroll
            for (int ni = 0; ni < 4; ++ni) {
                int col = cb * 128 + wc + ni * 16 + l16;
                b[ni] = *(const h8_t*)(Wt2 + (size_t)col * HID + ks * 32 + lq * 8);
            }
#pragma unroll
            for (int mi = 0; mi < 4; ++mi)
#pragma unroll
                for (int ni = 0; ni < 4; ++ni)
                    acc[mi][ni] = __builtin_amdgcn_mfma_f32_16x16x32_f16(a[mi], b[ni], acc[mi][ni], 0, 0, 0);
        }
#pragma unroll
        for (int ni = 0; ni < 4; ++ni) {
            int col = cb * 128 + wc + ni * 16 + l16;
            float bv = b2[col];
#pragma unroll
            for (int mi = 0; mi < 4; ++mi) {
                int rb = row0 + wr + mi * 16 + lq * 4;
#pragma unroll
                for (int r = 0; r < 4; ++r) {
                    int row = rb + r;
                    if (row < M) {
                        float v = fmaxf(acc[mi][ni][r] + bv, 0.f);
                        outh[(size_t)row * HID + col] = (_Float16)v;
                        if (writef) outf[(size_t)row * HID + col] = v;
                    }
                }
            }
        }
    }
}

// mean pool from zh: 1024 thr/block, 32 rows in flight x 32 h8 chunks, LDS reduce
__global__ __launch_bounds__(1024) void pool_kernel(const _Float16* __restrict__ zh,
                                                    const int* __restrict__ batch, int N,
                                                    float* __restrict__ g) {
    __shared__ float red[32 * 32 * 8];   // 32 KB
    int gid = blockIdx.x;
    int lo = 0, hi = N;
    while (lo < hi) { int mid = (lo + hi) >> 1; if (batch[mid] < gid) lo = mid + 1; else hi = mid; }
    int start = lo;
    int lo2 = start, hi2 = N;
    while (lo2 < hi2) { int mid = (lo2 + hi2) >> 1; if (batch[mid] < gid + 1) lo2 = mid + 1; else hi2 = mid; }
    int end = lo2;
    int cnt = end - start;

    int r = threadIdx.x >> 5;    // 0..31 row slot
    int ch = threadIdx.x & 31;   // chunk (8 fp16)
    float acc[8] = {};
    for (int row = start + r; row < end; row += 32) {
        h8_t v = *(const h8_t*)(zh + (size_t)row * HID + ch * 8);
#pragma unroll
        for (int j = 0; j < 8; ++j) acc[j] += (float)v[j];
    }
    float* slot = red + (r * 32 + ch) * 8;
#pragma unroll
    for (int j = 0; j < 8; ++j) slot[j] = acc[j];
    __syncthreads();
    for (int off = 16; off > 0; off >>= 1) {
        if (r < off) {
            const float* o = red + ((r + off) * 32 + ch) * 8;
#pragma unroll
            for (int j = 0; j < 8; ++j) { acc[j] += o[j]; slot[j] = acc[j]; }
        }
        __syncthreads();
    }
    if (r == 0) {
        float inv = 1.0f / fmaxf((float)cnt, 1.0f);
#pragma unroll
        for (int j = 0; j < 8; ++j) g[(size_t)gid * HID + ch * 8 + j] = acc[j] * inv;
    }
}

extern "C" void kernel_launch(void* const* d_in, const int* in_sizes, int n_in,
                              void* d_out, int out_size, void* d_ws, size_t ws_size,
                              hipStream_t stream) {
    const int* x = (const int*)d_in[0];
    const int* ei = (const int*)d_in[1];
    const int* ea = (const int*)d_in[2];
    const int* batch = (const int*)d_in[3];
    const float* xe1 = (const float*)d_in[4];
    const float* xe2 = (const float*)d_in[5];
    const float* ee1 = (const float*)d_in[6];
    const float* ee2 = (const float*)d_in[7];
    const float* W1 = (const float*)d_in[8];
    const float* b1 = (const float*)d_in[9];
    const float* W2 = (const float*)d_in[10];
    const float* b2 = (const float*)d_in[11];

    int N = in_sizes[0] / 2;
    int E = in_sizes[1] / 2;
    int G = out_size / HID - N;
    int nbm = (N + 127) / 128;
    int Np = nbm * 128;

    float* z = (float*)d_out;                       // [N,256] fp32 (final layer)
    float* gout = z + (size_t)N * HID;              // [G,256]

    char* w = (char*)d_ws;
    _Float16* h0h = (_Float16*)w;  w += (size_t)Np * HID * 2;
    _Float16* zh  = (_Float16*)w;  w += (size_t)Np * HID * 2;
    _Float16* Wt1 = (_Float16*)w;  w += (size_t)5 * HID * HID * 2;
    _Float16* Wt2 = (_Float16*)w;  w += (size_t)5 * HID * HID * 2;
    _Float16* etabh = (_Float16*)w; w += (size_t)NCODES * HID * 2;
    int* deg = (int*)w;       w += (size_t)N * 4;
    int* row_start = (int*)w; w += (size_t)(N + 1) * 4;
    int* cursor = (int*)w;    w += (size_t)N * 4;
    int* psum = (int*)w;      w += 64 * 4;
    unsigned* csr = (unsigned*)w;

    hipMemsetAsync(deg, 0, (size_t)N * 4, stream);
    etab_kernel<<<NCODES, HID, 0, stream>>>(ee1, ee2, etabh);
    embed_kernel<<<(N + 3) / 4, 256, 0, stream>>>(x, xe1, xe2, zh, N);
    prep_w<<<dim3(8, 8, 5), 256, 0, stream>>>(W1, Wt1);
    prep_w<<<dim3(8, 8, 5), 256, 0, stream>>>(W2, Wt2);
    hist_kernel<<<(E + 255) / 256, 256, 0, stream>>>(ei, E, deg);
    int nchunks = (N + SCAN_CHUNK - 1) / SCAN_CHUNK;
    scan_partial<<<nchunks, 256, 0, stream>>>(deg, N, psum);
    scan_sums<<<1, 1, 0, stream>>>(psum, nchunks);
    scan_apply<<<nchunks, 256, 0, stream>>>(deg, N, psum, row_start, cursor, E);
    fill_kernel<<<(E + 255) / 256, 256, 0, stream>>>(ei, ea, E, cursor, csr);

    for (int l = 0; l < 5; l++) {
        agg_kernel<<<(N + 7) / 8, 256, 0, stream>>>(zh, row_start, csr, etabh, h0h, N);
        mlp_fused<<<nbm, 256, 0, stream>>>(h0h, Wt1 + (size_t)l * HID * HID,
                                           b1 + (size_t)l * HID,
                                           Wt2 + (size_t)l * HID * HID,
                                           b2 + (size_t)l * HID,
                                           zh, z, N, (l == 4) ? 1 : 0);
    }
    pool_kernel<<<G, 1024, 0, stream>>>(zh, batch, N, gout);
}

// Round 4
// 1279.518 us; speedup vs baseline: 2.6553x; 1.3349x over previous
//
#include <hip/hip_runtime.h>
#include <hip/hip_bf16.h>

#define HID 256
#define NCODES 18
#define SCAN_CHUNK 2048
#define LROW 264   // LDS row stride in fp16 (33 chunks of 8) -> conflict-free spread

typedef _Float16 h8_t __attribute__((ext_vector_type(8)));
typedef _Float16 h4_t __attribute__((ext_vector_type(4)));
typedef float f4_t __attribute__((ext_vector_type(4)));

// e-table: 18 distinct edge embeddings = ee1[a0] + ee2[a1], fp16
__global__ void etab_kernel(const float* __restrict__ ee1, const float* __restrict__ ee2,
                            _Float16* __restrict__ etab) {
    int t = blockIdx.x;
    int c = threadIdx.x;
    etab[t * HID + c] = (_Float16)(ee1[(t / 3) * HID + c] + ee2[(t % 3) * HID + c]);
}

// zh[n] = fp16(xe1[x[n,0]] + xe2[x[n,1]])
__global__ __launch_bounds__(256) void embed_kernel(const int* __restrict__ x,
                                                    const float* __restrict__ xe1,
                                                    const float* __restrict__ xe2,
                                                    _Float16* __restrict__ zh, int N) {
    int node = blockIdx.x * 4 + (threadIdx.x >> 6);
    int lane = threadIdx.x & 63;
    if (node >= N) return;
    int a0 = x[node * 2 + 0];
    int a1 = x[node * 2 + 1];
    const float4 u = *(const float4*)(xe1 + (size_t)a0 * HID + lane * 4);
    const float4 v = *(const float4*)(xe2 + (size_t)a1 * HID + lane * 4);
    h4_t r;
    r.x = (_Float16)(u.x + v.x); r.y = (_Float16)(u.y + v.y);
    r.z = (_Float16)(u.z + v.z); r.w = (_Float16)(u.w + v.w);
    *(h4_t*)(zh + (size_t)node * HID + lane * 4) = r;
}

// W [5][256][256] fp32 row-major -> Wt fp16 transposed (Wt[n][k]=W[k][n])
__global__ __launch_bounds__(256) void prep_w(const float* __restrict__ W,
                                              _Float16* __restrict__ Wt) {
    __shared__ float t[32][33];
    int m = blockIdx.z;
    int tx = threadIdx.x & 31, ty = threadIdx.x >> 5;
    const float* Wm = W + (size_t)m * HID * HID;
    _Float16* Wtm = Wt + (size_t)m * HID * HID;
    int k0 = blockIdx.x * 32, n0 = blockIdx.y * 32;
#pragma unroll
    for (int j = 0; j < 4; ++j) { int r = ty + j * 8; t[r][tx] = Wm[(k0 + r) * HID + n0 + tx]; }
    __syncthreads();
#pragma unroll
    for (int j = 0; j < 4; ++j) { int r = ty + j * 8; Wtm[(size_t)(n0 + r) * HID + k0 + tx] = (_Float16)t[tx][r]; }
}

__global__ void hist_kernel(const int* __restrict__ ei, int E, int* __restrict__ deg) {
    int i = blockIdx.x * 256 + threadIdx.x;
    if (i < E) atomicAdd(&deg[ei[E + i]], 1);
}

__global__ __launch_bounds__(256) void scan_partial(const int* __restrict__ deg, int n,
                                                    int* __restrict__ psum) {
    __shared__ int red[256];
    int base = blockIdx.x * SCAN_CHUNK;
    int s = 0;
    for (int i = threadIdx.x; i < SCAN_CHUNK; i += 256) {
        int idx = base + i;
        if (idx < n) s += deg[idx];
    }
    red[threadIdx.x] = s;
    __syncthreads();
    for (int off = 128; off > 0; off >>= 1) {
        if (threadIdx.x < off) red[threadIdx.x] += red[threadIdx.x + off];
        __syncthreads();
    }
    if (threadIdx.x == 0) psum[blockIdx.x] = red[0];
}

__global__ void scan_sums(int* psum, int nchunks) {
    if (blockIdx.x == 0 && threadIdx.x == 0) {
        int acc = 0;
        for (int i = 0; i < nchunks; i++) { int v = psum[i]; psum[i] = acc; acc += v; }
    }
}

__global__ __launch_bounds__(256) void scan_apply(const int* __restrict__ deg, int n,
                                                  const int* __restrict__ psum,
                                                  int* __restrict__ row_start,
                                                  int* __restrict__ cursor, int E) {
    __shared__ int tmp[256];
    int tid = threadIdx.x;
    int base = blockIdx.x * SCAN_CHUNK;
    int tb = base + tid * 8;
    int loc[8];
    int s = 0;
    for (int j = 0; j < 8; j++) {
        loc[j] = s;
        int idx = tb + j;
        if (idx < n) s += deg[idx];
    }
    tmp[tid] = s;
    __syncthreads();
    for (int off = 1; off < 256; off <<= 1) {
        int v = 0;
        if (tid >= off) v = tmp[tid - off];
        __syncthreads();
        if (tid >= off) tmp[tid] += v;
        __syncthreads();
    }
    int excl = tmp[tid] - s + psum[blockIdx.x];
    for (int j = 0; j < 8; j++) {
        int idx = tb + j;
        if (idx < n) {
            int v = excl + loc[j];
            row_start[idx] = v;
            cursor[idx] = v;
        }
    }
    if (blockIdx.x == 0 && tid == 0) row_start[n] = E;
}

__global__ void fill_kernel(const int* __restrict__ ei, const int* __restrict__ ea, int E,
                            int* __restrict__ cursor, unsigned* __restrict__ csr) {
    int i = blockIdx.x * 256 + threadIdx.x;
    if (i >= E) return;
    int dst = ei[E + i];
    int src = ei[i];
    int code = ea[i * 2] * 3 + ea[i * 2 + 1];
    int p = atomicAdd(&cursor[dst], 1);
    csr[p] = (unsigned)src | ((unsigned)code << 20);
}

// h0h[n] = fp16( zh[n] + sum_in relu(zh[src]+etab[code]) )
// 2 nodes per wave (32 lanes each, 16B loads), edge loop unrolled x2.
__global__ __launch_bounds__(256) void agg_kernel(const _Float16* __restrict__ zh,
                                                  const int* __restrict__ row_start,
                                                  const unsigned* __restrict__ csr,
                                                  const _Float16* __restrict__ etab,
                                                  _Float16* __restrict__ h0h, int N) {
    int tid = threadIdx.x;
    int node = blockIdx.x * 8 + (tid >> 5);
    int l32 = tid & 31;
    if (node >= N) return;
    h8_t self = *(const h8_t*)(zh + (size_t)node * HID + l32 * 8);
    float acc[8];
#pragma unroll
    for (int j = 0; j < 8; ++j) acc[j] = (float)self[j];
    int s = row_start[node];
    int e = row_start[node + 1];
    int i = s;
    for (; i + 2 <= e; i += 2) {
        unsigned p0 = csr[i], p1 = csr[i + 1];
        h8_t z0 = *(const h8_t*)(zh + (size_t)(p0 & 0xFFFFF) * HID + l32 * 8);
        h8_t e0 = *(const h8_t*)(etab + (size_t)(p0 >> 20) * HID + l32 * 8);
        h8_t z1 = *(const h8_t*)(zh + (size_t)(p1 & 0xFFFFF) * HID + l32 * 8);
        h8_t e1 = *(const h8_t*)(etab + (size_t)(p1 >> 20) * HID + l32 * 8);
#pragma unroll
        for (int j = 0; j < 8; ++j) {
            acc[j] += fmaxf((float)z0[j] + (float)e0[j], 0.f);
            acc[j] += fmaxf((float)z1[j] + (float)e1[j], 0.f);
        }
    }
    if (i < e) {
        unsigned p0 = csr[i];
        h8_t z0 = *(const h8_t*)(zh + (size_t)(p0 & 0xFFFFF) * HID + l32 * 8);
        h8_t e0 = *(const h8_t*)(etab + (size_t)(p0 >> 20) * HID + l32 * 8);
#pragma unroll
        for (int j = 0; j < 8; ++j) acc[j] += fmaxf((float)z0[j] + (float)e0[j], 0.f);
    }
    h8_t o;
#pragma unroll
    for (int j = 0; j < 8; ++j) o[j] = (_Float16)acc[j];
    *(h8_t*)(h0h + (size_t)node * HID + l32 * 8) = o;
}

// Fused MLP: z = relu( relu(A@W1+b1) @ W2 + b2 ).
// BM=64 rows/block, 4 waves x 64-col stripes, ~68KB LDS -> 2 blocks/CU.
// Stride-33-chunk LDS rows (conflict-free). Coalesced h8 epilogue via As reuse.
__global__ __launch_bounds__(256, 2) void mlp_fused(const _Float16* __restrict__ A,
                                                    const _Float16* __restrict__ Wt1,
                                                    const float* __restrict__ b1,
                                                    const _Float16* __restrict__ Wt2,
                                                    const float* __restrict__ b2,
                                                    _Float16* __restrict__ outh,
                                                    float* __restrict__ outf,
                                                    int M, int writef) {
    __shared__ _Float16 As[64 * LROW];   // ~33.8 KB
    __shared__ _Float16 Ys[64 * LROW];   // ~33.8 KB
    int tid = threadIdx.x;
    int lane = tid & 63;
    int w = tid >> 6;
    int row0 = blockIdx.x * 64;
    const _Float16* Ab = A + (size_t)row0 * HID;

    // stage 64x256 fp16 tile (16B/lane, linear-per-row, stride-33 chunks)
#pragma unroll
    for (int it = 0; it < 8; ++it) {
        int c = it * 256 + tid;
        int row = c >> 5, cir = c & 31;
        h8_t v = *(const h8_t*)(Ab + row * HID + cir * 8);
        *(h8_t*)(As + row * LROW + cir * 8) = v;
    }
    __syncthreads();

    int wc = w * 64;
    int l16 = lane & 15;
    int lq = lane >> 4;

    // ---- GEMM1: y = relu(A@W1+b1) -> Ys ----
    {
        f4_t acc[4][4] = {};
#pragma unroll
        for (int ks = 0; ks < 8; ++ks) {
            h8_t a[4], b[4];
#pragma unroll
            for (int mi = 0; mi < 4; ++mi)
                a[mi] = *(const h8_t*)(As + (mi * 16 + l16) * LROW + (ks * 4 + lq) * 8);
#pragma unroll
            for (int ni = 0; ni < 4; ++ni)
                b[ni] = *(const h8_t*)(Wt1 + (size_t)(wc + ni * 16 + l16) * HID + ks * 32 + lq * 8);
#pragma unroll
            for (int mi = 0; mi < 4; ++mi)
#pragma unroll
                for (int ni = 0; ni < 4; ++ni)
                    acc[mi][ni] = __builtin_amdgcn_mfma_f32_16x16x32_f16(a[mi], b[ni], acc[mi][ni], 0, 0, 0);
        }
#pragma unroll
        for (int ni = 0; ni < 4; ++ni) {
            int col = wc + ni * 16 + l16;
            float bv = b1[col];
#pragma unroll
            for (int mi = 0; mi < 4; ++mi)
#pragma unroll
                for (int r = 0; r < 4; ++r) {
                    int rr = mi * 16 + lq * 4 + r;
                    Ys[rr * LROW + col] = (_Float16)fmaxf(acc[mi][ni][r] + bv, 0.f);
                }
        }
    }
    __syncthreads();

    // ---- GEMM2: z = relu(y@W2+b2) -> As (reuse, linear) ----
    {
        f4_t acc[4][4] = {};
#pragma unroll
        for (int ks = 0; ks < 8; ++ks) {
            h8_t a[4], b[4];
#pragma unroll
            for (int mi = 0; mi < 4; ++mi)
                a[mi] = *(const h8_t*)(Ys + (mi * 16 + l16) * LROW + (ks * 4 + lq) * 8);
#pragma unroll
            for (int ni = 0; ni < 4; ++ni)
                b[ni] = *(const h8_t*)(Wt2 + (size_t)(wc + ni * 16 + l16) * HID + ks * 32 + lq * 8);
#pragma unroll
            for (int mi = 0; mi < 4; ++mi)
#pragma unroll
                for (int ni = 0; ni < 4; ++ni)
                    acc[mi][ni] = __builtin_amdgcn_mfma_f32_16x16x32_f16(a[mi], b[ni], acc[mi][ni], 0, 0, 0);
        }
#pragma unroll
        for (int ni = 0; ni < 4; ++ni) {
            int col = wc + ni * 16 + l16;
            float bv = b2[col];
#pragma unroll
            for (int mi = 0; mi < 4; ++mi)
#pragma unroll
                for (int r = 0; r < 4; ++r) {
                    int rr = mi * 16 + lq * 4 + r;
                    As[rr * LROW + col] = (_Float16)fmaxf(acc[mi][ni][r] + bv, 0.f);
                }
        }
    }
    __syncthreads();

    // ---- coalesced store: 16B/lane fp16 (+32B/lane fp32 on last layer) ----
#pragma unroll
    for (int it = 0; it < 8; ++it) {
        int c = it * 256 + tid;
        int row = c >> 5, cir = c & 31;
        int grow = row0 + row;
        if (grow < M) {
            h8_t v = *(const h8_t*)(As + row * LROW + cir * 8);
            *(h8_t*)(outh + (size_t)grow * HID + cir * 8) = v;
            if (writef) {
                f4_t f0, f1;
#pragma unroll
                for (int j = 0; j < 4; ++j) { f0[j] = (float)v[j]; f1[j] = (float)v[j + 4]; }
                *(f4_t*)(outf + (size_t)grow * HID + cir * 8) = f0;
                *(f4_t*)(outf + (size_t)grow * HID + cir * 8 + 4) = f1;
            }
        }
    }
}

// mean pool from zh: 1024 thr/block, 32 rows in flight x 32 h8 chunks, LDS reduce
__global__ __launch_bounds__(1024) void pool_kernel(const _Float16* __restrict__ zh,
                                                    const int* __restrict__ batch, int N,
                                                    float* __restrict__ g) {
    __shared__ float red[32 * 32 * 8];
    int gid = blockIdx.x;
    int lo = 0, hi = N;
    while (lo < hi) { int mid = (lo + hi) >> 1; if (batch[mid] < gid) lo = mid + 1; else hi = mid; }
    int start = lo;
    int lo2 = start, hi2 = N;
    while (lo2 < hi2) { int mid = (lo2 + hi2) >> 1; if (batch[mid] < gid + 1) lo2 = mid + 1; else hi2 = mid; }
    int end = lo2;
    int cnt = end - start;

    int r = threadIdx.x >> 5;
    int ch = threadIdx.x & 31;
    float acc[8] = {};
    for (int row = start + r; row < end; row += 32) {
        h8_t v = *(const h8_t*)(zh + (size_t)row * HID + ch * 8);
#pragma unroll
        for (int j = 0; j < 8; ++j) acc[j] += (float)v[j];
    }
    float* slot = red + (r * 32 + ch) * 8;
#pragma unroll
    for (int j = 0; j < 8; ++j) slot[j] = acc[j];
    __syncthreads();
    for (int off = 16; off > 0; off >>= 1) {
        if (r < off) {
            const float* o = red + ((r + off) * 32 + ch) * 8;
#pragma unroll
            for (int j = 0; j < 8; ++j) { acc[j] += o[j]; slot[j] = acc[j]; }
        }
        __syncthreads();
    }
    if (r == 0) {
        float inv = 1.0f / fmaxf((float)cnt, 1.0f);
#pragma unroll
        for (int j = 0; j < 8; ++j) g[(size_t)gid * HID + ch * 8 + j] = acc[j] * inv;
    }
}

extern "C" void kernel_launch(void* const* d_in, const int* in_sizes, int n_in,
                              void* d_out, int out_size, void* d_ws, size_t ws_size,
                              hipStream_t stream) {
    const int* x = (const int*)d_in[0];
    const int* ei = (const int*)d_in[1];
    const int* ea = (const int*)d_in[2];
    const int* batch = (const int*)d_in[3];
    const float* xe1 = (const float*)d_in[4];
    const float* xe2 = (const float*)d_in[5];
    const float* ee1 = (const float*)d_in[6];
    const float* ee2 = (const float*)d_in[7];
    const float* W1 = (const float*)d_in[8];
    const float* b1 = (const float*)d_in[9];
    const float* W2 = (const float*)d_in[10];
    const float* b2 = (const float*)d_in[11];

    int N = in_sizes[0] / 2;
    int E = in_sizes[1] / 2;
    int G = out_size / HID - N;
    int Np = ((N + 127) / 128) * 128;   // padded rows for staging overreach
    int nbm = (N + 63) / 64;

    float* z = (float*)d_out;                       // [N,256] fp32 (final layer)
    float* gout = z + (size_t)N * HID;              // [G,256]

    char* w = (char*)d_ws;
    _Float16* h0h = (_Float16*)w;  w += (size_t)Np * HID * 2;
    _Float16* zh  = (_Float16*)w;  w += (size_t)Np * HID * 2;
    _Float16* Wt1 = (_Float16*)w;  w += (size_t)5 * HID * HID * 2;
    _Float16* Wt2 = (_Float16*)w;  w += (size_t)5 * HID * HID * 2;
    _Float16* etabh = (_Float16*)w; w += (size_t)NCODES * HID * 2;
    int* deg = (int*)w;       w += (size_t)N * 4;
    int* row_start = (int*)w; w += (size_t)(N + 1) * 4;
    int* cursor = (int*)w;    w += (size_t)N * 4;
    int* psum = (int*)w;      w += 64 * 4;
    unsigned* csr = (unsigned*)w;

    hipMemsetAsync(deg, 0, (size_t)N * 4, stream);
    etab_kernel<<<NCODES, HID, 0, stream>>>(ee1, ee2, etabh);
    embed_kernel<<<(N + 3) / 4, 256, 0, stream>>>(x, xe1, xe2, zh, N);
    prep_w<<<dim3(8, 8, 5), 256, 0, stream>>>(W1, Wt1);
    prep_w<<<dim3(8, 8, 5), 256, 0, stream>>>(W2, Wt2);
    hist_kernel<<<(E + 255) / 256, 256, 0, stream>>>(ei, E, deg);
    int nchunks = (N + SCAN_CHUNK - 1) / SCAN_CHUNK;
    scan_partial<<<nchunks, 256, 0, stream>>>(deg, N, psum);
    scan_sums<<<1, 1, 0, stream>>>(psum, nchunks);
    scan_apply<<<nchunks, 256, 0, stream>>>(deg, N, psum, row_start, cursor, E);
    fill_kernel<<<(E + 255) / 256, 256, 0, stream>>>(ei, ea, E, cursor, csr);

    for (int l = 0; l < 5; l++) {
        agg_kernel<<<(N + 7) / 8, 256, 0, stream>>>(zh, row_start, csr, etabh, h0h, N);
        mlp_fused<<<nbm, 256, 0, stream>>>(h0h, Wt1 + (size_t)l * HID * HID,
                                           b1 + (size_t)l * HID,
                                           Wt2 + (size_t)l * HID * HID,
                                           b2 + (size_t)l * HID,
                                           zh, z, N, (l == 4) ? 1 : 0);
    }
    pool_kernel<<<G, 1024, 0, stream>>>(zh, batch, N, gout);
}